// Round 4
// baseline (311.875 us; speedup 1.0000x reference)
//
#include <hip/hip_runtime.h>
#include <hip/hip_bf16.h>

#define N_NODES 50000
#define N_PAD   50048
#define N_EDGES 800000
#define E_TOT   850000
#define NB      1024
#define ESM_DIM 480
#define HD      128
#define NBUCK   196          // buckets of 256 dst nodes
#define CAP     5120         // fixed bucket capacity (mean 4352 + 12 sigma)
#define EPB     3321         // edges per scatter block (256 blocks)
#define SC_BLK  256
#define BND_BLK 196
#define WC_BLK  16
#define TAB_BLK 4
#define G1B     782          // N_PAD / 64
#define LSTM_B  96           // 16 m-tiles x 6 n-tiles (64x64 out per block)
#define LG      384          // lstm gate cols kept (i,g,o per direction)
#define AGG_GRID 12500
#define NL_BLK  512

typedef short short8 __attribute__((ext_vector_type(8)));
typedef unsigned short ushort8 __attribute__((ext_vector_type(8)));
typedef float f32x4 __attribute__((ext_vector_type(4)));

__device__ __forceinline__ float bf2f(unsigned int u) {
    union { unsigned int i; float f; } c; c.i = u << 16; return c.f;
}
__device__ __forceinline__ unsigned short f2bf(float f) {
    union { float f; unsigned int i; } c; c.f = f;
    unsigned int i = c.i;
    return (unsigned short)((i + 0x7FFFu + ((i >> 16) & 1u)) >> 16);
}
__device__ __forceinline__ void split2(float v, unsigned short& h, unsigned short& l) {
    h = f2bf(v);
    l = f2bf(v - bf2f(h));
}

// ================= megaA parts (small-LDS roles only) =================

// scatter: register-cache the packed edges across both passes (no 2nd ei read)
__device__ void dev_scatter(const int* __restrict__ ei, int* __restrict__ gcur,
                            int* __restrict__ pairs, int blk) {
    __shared__ int hist[NBUCK];
    int t = threadIdx.x;
    for (int u = t; u < NBUCK; u += 256) hist[u] = 0;
    __syncthreads();
    int e0 = blk * EPB;
    int e1 = (e0 + EPB < E_TOT) ? e0 + EPB : E_TOT;
    int ec[13];                       // statically indexed -> stays in VGPRs
#pragma unroll
    for (int u = 0; u < 13; ++u) {
        int e = e0 + t + u * 256;
        if (e < e1) {
            int s, d;
            if (e < N_EDGES) { s = ei[e]; d = ei[N_EDGES + e]; }
            else             { s = d = e - N_EDGES; }
            int bu = d >> 8;
            ec[u] = s | ((d & 255) << 16) | (bu << 24);   // s<65536, bu<196
            atomicAdd(&hist[bu], 1);
        }
    }
    __syncthreads();
    for (int u = t; u < NBUCK; u += 256) {
        int c = hist[u];
        hist[u] = (c > 0) ? atomicAdd(&gcur[u], c) : 0;   // base within bucket
    }
    __syncthreads();
#pragma unroll
    for (int u = 0; u < 13; ++u) {
        int e = e0 + t + u * 256;
        if (e < e1) {
            int val = ec[u];
            int bu = ((unsigned)val) >> 24;
            int pos = atomicAdd(&hist[bu], 1);
            pairs[bu * CAP + pos] = val & 0xFFFFFF;
        }
    }
}

// gat1 as split-bf16 MFMA (f32 accuracy): h = X @ W^T, fused alpha epilogue.
// W converted f32->hi/lo in-register; zero LDS so it doesn't hurt megaA occupancy.
__device__ void dev_gat1_mfma(const float* __restrict__ X,
                              const float* __restrict__ W1,
                              const float* __restrict__ asrc, const float* __restrict__ adst,
                              unsigned short* __restrict__ out,
                              float* __restrict__ alpha_s, float* __restrict__ alpha_d,
                              int blk) {
    int t = threadIdx.x;
    int wid = t >> 6, L = t & 63, quad = L >> 4, lo = L & 15;
    int m0 = blk * 64 + wid * 16;
    int row = m0 + lo;
    const float* xr = X + (size_t)row * 21;
    int kbase = quad * 8;
    bool valid = row < N_NODES;
    short8 ah, al;
#pragma unroll
    for (int j = 0; j < 8; ++j) {
        int k = kbase + j;
        float v = (valid && k < 21) ? xr[k] : 0.f;
        unsigned short h, l;
        split2(v, h, l);
        ah[j] = (short)h; al[j] = (short)l;
    }
    float as_p[4] = {0.f, 0.f, 0.f, 0.f};
    float ad_p[4] = {0.f, 0.f, 0.f, 0.f};
#pragma unroll
    for (int ft = 0; ft < 8; ++ft) {
        const float* wr = W1 + (ft * 16 + lo) * 21;
        short8 bh, bl;
#pragma unroll
        for (int j = 0; j < 8; ++j) {
            int k = kbase + j;
            float v = (k < 21) ? wr[k] : 0.f;
            unsigned short h, l;
            split2(v, h, l);
            bh[j] = (short)h; bl[j] = (short)l;
        }
        f32x4 acc = {0.f, 0.f, 0.f, 0.f};
        acc = __builtin_amdgcn_mfma_f32_16x16x32_bf16(ah, bh, acc, 0, 0, 0);
        acc = __builtin_amdgcn_mfma_f32_16x16x32_bf16(al, bh, acc, 0, 0, 0);
        acc = __builtin_amdgcn_mfma_f32_16x16x32_bf16(ah, bl, acc, 0, 0, 0);
        float asv = asrc[ft * 16 + lo];
        float adv = adst[ft * 16 + lo];
#pragma unroll
        for (int r = 0; r < 4; ++r) {
            int m = m0 + quad * 4 + r;
            out[(size_t)m * HD + ft * 16 + lo] = f2bf(acc[r]);   // pad rows -> 0
            as_p[r] += acc[r] * asv;
            ad_p[r] += acc[r] * adv;
        }
    }
#pragma unroll
    for (int off = 1; off < 16; off <<= 1) {
#pragma unroll
        for (int r = 0; r < 4; ++r) {
            as_p[r] += __shfl_xor(as_p[r], off);
            ad_p[r] += __shfl_xor(ad_p[r], off);
        }
    }
    if (lo == 0) {
#pragma unroll
        for (int r = 0; r < 4; ++r) {
            int m = m0 + quad * 4 + r;
            if (m < N_NODES) { alpha_s[m] = as_p[r]; alpha_d[m] = ad_p[r]; }
        }
    }
}

// tab branch: 4 blocks x 256 thr, block handles 16 cols; recompute (no big reg array)
__device__ void dev_tab4(const float* __restrict__ tf, const float* __restrict__ W,
                         const float* __restrict__ bias, const float* __restrict__ g,
                         const float* __restrict__ b, float* __restrict__ z, int blk) {
    __shared__ float ssum[16][16];
    __shared__ float ssq[16][16];
    int t = threadIdx.x;
    int rg = t >> 4, jl = t & 15;
    int j = blk * 16 + jl;
    float Wj[7];
#pragma unroll
    for (int k = 0; k < 7; ++k) Wj[k] = W[j * 7 + k];
    float bj = bias[j];
    float s = 0.f, q = 0.f;
    for (int rr = 0; rr < 64; ++rr) {
        int row = rg * 64 + rr;
        const float* xp = &tf[(size_t)row * 7];
        float a = bj;
#pragma unroll
        for (int k = 0; k < 7; ++k) a += xp[k] * Wj[k];
        s += a; q += a * a;
    }
    ssum[rg][jl] = s; ssq[rg][jl] = q;
    __syncthreads();
    for (int off = 8; off; off >>= 1) {
        if (rg < off) { ssum[rg][jl] += ssum[rg + off][jl]; ssq[rg][jl] += ssq[rg + off][jl]; }
        __syncthreads();
    }
    float mu = ssum[0][jl] * (1.f / 1024.f);
    float var = ssq[0][jl] * (1.f / 1024.f) - mu * mu;
    float sc = rsqrtf(var + 1e-5f) * g[j];
    float sh = b[j] - mu * sc;
    for (int rr = 0; rr < 64; ++rr) {
        int row = rg * 64 + rr;
        const float* xp = &tf[(size_t)row * 7];
        float a = bj;
#pragma unroll
        for (int k = 0; k < 7; ++k) a += xp[k] * Wj[k];
        z[(size_t)row * 320 + 256 + j] = fmaxf(a * sc + sh, 0.f);
    }
}

__global__ __launch_bounds__(256) void megaA(
        const int* __restrict__ ei, int* __restrict__ gcur, int* __restrict__ pairs,
        const float* __restrict__ x, const float* __restrict__ gat1_W,
        const float* __restrict__ gat1_as, const float* __restrict__ gat1_ad,
        unsigned short* __restrict__ h0, float* __restrict__ alpha_s, float* __restrict__ alpha_d,
        const int* __restrict__ batch, int* __restrict__ gstart,
        const float* __restrict__ W2, unsigned short* __restrict__ Wb,
        const float* __restrict__ tf, const float* __restrict__ tab_W,
        const float* __restrict__ tab_b, const float* __restrict__ tab_g,
        const float* __restrict__ tab_bb, float* __restrict__ z) {
    int b = blockIdx.x, t = threadIdx.x;
    if (b < SC_BLK) {
        dev_scatter(ei, gcur, pairs, b);
    } else if (b < SC_BLK + G1B) {
        dev_gat1_mfma(x, gat1_W, gat1_as, gat1_ad, h0, alpha_s, alpha_d, b - SC_BLK);
    } else if (b < SC_BLK + G1B + BND_BLK) {
        int i = (b - (SC_BLK + G1B)) * 256 + t;
        if (i >= N_NODES) return;
        int bb = batch[i];
        int bp = (i == 0) ? -1 : batch[i - 1];
        for (int g = bp + 1; g <= bb; ++g) gstart[g] = i;
        if (i == N_NODES - 1)
            for (int g = bb + 1; g <= NB; ++g) gstart[g] = N_NODES;
    } else if (b < SC_BLK + G1B + BND_BLK + WC_BLK) {
        int i = (b - (SC_BLK + G1B + BND_BLK)) * 256 + t;
        if (i >= 128 * 32) return;
        float4 v = ((const float4*)W2)[i];
        ((ushort4*)Wb)[i] = make_ushort4(f2bf(v.x), f2bf(v.y), f2bf(v.z), f2bf(v.w));
    } else {
        dev_tab4(tf, tab_W, tab_b, tab_g, tab_bb, z,
                 b - (SC_BLK + G1B + BND_BLK + WC_BLK));
    }
}

// ================= megaB: bucket CSR | lstm MFMA (big-LDS role isolated here) ====

__device__ __forceinline__ float sigmoidf_(float x) { return 1.f / (1.f + __expf(-x)); }

// lstm gates: G[1024][384] = esm @ Wg^T (i,g,o), split-bf16 MFMA.
// B staged f32 -> LDS hi/lo with on-the-fly conversion; A converted in-register.
__device__ void dev_lstm_mfma(const float* __restrict__ esm,
                              const float* __restrict__ Wf,
                              const float* __restrict__ Wr,
                              float* __restrict__ G, int blk) {
    __shared__ unsigned short Bsh[64][104];
    __shared__ unsigned short Bsl[64][104];
    int t = threadIdx.x;
    int wid = t >> 6, L = t & 63, quad = L >> 4, lo = L & 15;
    int nt = blk % 6, mt = blk / 6;
    int m0 = mt * 64 + wid * 16;
    int n0 = nt * 64;
    f32x4 accs[4];
#pragma unroll
    for (int ft = 0; ft < 4; ++ft) accs[ft] = (f32x4){0.f, 0.f, 0.f, 0.f};
    const float* ar = esm + (size_t)(m0 + lo) * ESM_DIM;
    for (int c = 0; c < 5; ++c) {
        int k0c = c * 96;
        // per-wave A fragments: f32 load + in-reg split
        short8 ah[3], al[3];
#pragma unroll
        for (int ks = 0; ks < 3; ++ks) {
            const float* ap = &ar[k0c + ks * 32 + quad * 8];
            float4 v0 = *(const float4*)ap;
            float4 v1 = *(const float4*)(ap + 4);
            float av[8] = {v0.x, v0.y, v0.z, v0.w, v1.x, v1.y, v1.z, v1.w};
#pragma unroll
            for (int j = 0; j < 8; ++j) {
                unsigned short h, l;
                split2(av[j], h, l);
                ah[ks][j] = (short)h; al[ks][j] = (short)l;
            }
        }
        // cooperative stage of B tile: 64 gathered gate rows x 96 cols, f32 -> hi/lo
#pragma unroll
        for (int u = 0; u < 6; ++u) {
            int li = u * 256 + t;              // float4 units: 64*24 = 1536
            int rowb = li / 24, colb = (li % 24) * 4;
            int n = n0 + rowb;
            int rr = (n >= 192) ? n - 192 : n;
            const float* Wsrc = (n >= 192) ? Wr : Wf;
            int srow = (rr < 64) ? rr : rr + 64;       // gate map i,g,o
            float4 v = *(const float4*)&Wsrc[(size_t)srow * ESM_DIM + k0c + colb];
            ushort4 h, l;
            split2(v.x, h.x, l.x); split2(v.y, h.y, l.y);
            split2(v.z, h.z, l.z); split2(v.w, h.w, l.w);
            *(ushort4*)&Bsh[rowb][colb] = h;
            *(ushort4*)&Bsl[rowb][colb] = l;
        }
        __syncthreads();
#pragma unroll
        for (int ks = 0; ks < 3; ++ks) {
#pragma unroll
            for (int ft = 0; ft < 4; ++ft) {
                short8 bh = *(const short8*)&Bsh[ft * 16 + lo][ks * 32 + quad * 8];
                short8 bl = *(const short8*)&Bsl[ft * 16 + lo][ks * 32 + quad * 8];
                accs[ft] = __builtin_amdgcn_mfma_f32_16x16x32_bf16(ah[ks], bh, accs[ft], 0, 0, 0);
                accs[ft] = __builtin_amdgcn_mfma_f32_16x16x32_bf16(al[ks], bh, accs[ft], 0, 0, 0);
                accs[ft] = __builtin_amdgcn_mfma_f32_16x16x32_bf16(ah[ks], bl, accs[ft], 0, 0, 0);
            }
        }
        __syncthreads();
    }
#pragma unroll
    for (int ft = 0; ft < 4; ++ft) {
#pragma unroll
        for (int r = 0; r < 4; ++r)
            G[(size_t)(m0 + quad * 4 + r) * LG + n0 + ft * 16 + lo] = accs[ft][r];
    }
}

__global__ __launch_bounds__(256) void megaB(
        const int* __restrict__ gcur, const int* __restrict__ pairs,
        int* __restrict__ row_beg, int* __restrict__ row_end, int* __restrict__ csr_src,
        const float* __restrict__ esm, const float* __restrict__ Wih_f,
        const float* __restrict__ Wih_r, float* __restrict__ g_lstm) {
    int b = blockIdx.x, t = threadIdx.x;
    if (b >= NBUCK) {
        dev_lstm_mfma(esm, Wih_f, Wih_r, g_lstm, b - NBUCK);
        return;
    }
    __shared__ int dc[256];
    __shared__ int wt[4];
    __shared__ int cur[256];
    int rs = b * CAP;
    int re = rs + gcur[b];
    dc[t] = 0;
    __syncthreads();
    // pass 1: per-dst histogram, 4-way unrolled loads
    for (int i = rs + t; i < re; i += 1024) {
        int i1 = i + 256, i2 = i + 512, i3 = i + 768;
        int p0 = pairs[i];
        int p1 = (i1 < re) ? pairs[i1] : 0;
        int p2 = (i2 < re) ? pairs[i2] : 0;
        int p3 = (i3 < re) ? pairs[i3] : 0;
        atomicAdd(&dc[p0 >> 16], 1);
        if (i1 < re) atomicAdd(&dc[p1 >> 16], 1);
        if (i2 < re) atomicAdd(&dc[p2 >> 16], 1);
        if (i3 < re) atomicAdd(&dc[p3 >> 16], 1);
    }
    __syncthreads();
    int v = dc[t];
    int lane = t & 63, wid = t >> 6;
    int sc = v;
#pragma unroll
    for (int off = 1; off < 64; off <<= 1) {
        int n = __shfl_up(sc, off);
        if (lane >= off) sc += n;
    }
    if (lane == 63) wt[wid] = sc;
    __syncthreads();
    int pref = 0;
    for (int ww = 0; ww < wid; ++ww) pref += wt[ww];
    int beg = rs + pref + sc - v;
    int node = b * 256 + t;
    if (node < N_NODES) { row_beg[node] = beg; row_end[node] = beg + v; }
    cur[t] = beg;
    __syncthreads();
    // pass 2: positioning, 4-way unrolled loads
    for (int i = rs + t; i < re; i += 1024) {
        int i1 = i + 256, i2 = i + 512, i3 = i + 768;
        int p0 = pairs[i];
        int p1 = (i1 < re) ? pairs[i1] : 0;
        int p2 = (i2 < re) ? pairs[i2] : 0;
        int p3 = (i3 < re) ? pairs[i3] : 0;
        int pos0 = atomicAdd(&cur[p0 >> 16], 1);
        csr_src[pos0] = p0 & 0xFFFF;
        if (i1 < re) { int pos = atomicAdd(&cur[p1 >> 16], 1); csr_src[pos] = p1 & 0xFFFF; }
        if (i2 < re) { int pos = atomicAdd(&cur[p2 >> 16], 1); csr_src[pos] = p2 & 0xFFFF; }
        if (i3 < re) { int pos = atomicAdd(&cur[p3 >> 16], 1); csr_src[pos] = p3 & 0xFFFF; }
    }
}

// ================= GAT2 linear: MFMA + fused alpha epilogue =================

__global__ __launch_bounds__(256) void gemm_mfma(const unsigned short* __restrict__ A,
                                                 const unsigned short* __restrict__ Wb,
                                                 const float* __restrict__ asrc,
                                                 const float* __restrict__ adst,
                                                 unsigned short* __restrict__ out,
                                                 float* __restrict__ alpha_s,
                                                 float* __restrict__ alpha_d, int M) {
    __shared__ unsigned short Wlds[128 * 136];
    int t = threadIdx.x;
    for (int u = t; u < 128 * 16; u += 256) {
        int row = u >> 4, seg = u & 15;
        *(ushort8*)&Wlds[row * 136 + seg * 8] = *(const ushort8*)&Wb[row * 128 + seg * 8];
    }
    __syncthreads();
    int wid = t >> 6, L = t & 63;
    int quad = L >> 4, lo = L & 15;
    int m0 = blockIdx.x * 64 + wid * 16;
    short8 afrag[4];
#pragma unroll
    for (int ch = 0; ch < 4; ++ch)
        afrag[ch] = *(const short8*)&A[(size_t)(m0 + lo) * HD + ch * 32 + quad * 8];
    float as_p[4] = {0.f, 0.f, 0.f, 0.f};
    float ad_p[4] = {0.f, 0.f, 0.f, 0.f};
#pragma unroll
    for (int ft = 0; ft < 8; ++ft) {
        f32x4 acc = {0.f, 0.f, 0.f, 0.f};
#pragma unroll
        for (int ch = 0; ch < 4; ++ch) {
            short8 b = *(const short8*)&Wlds[(ft * 16 + lo) * 136 + ch * 32 + quad * 8];
            acc = __builtin_amdgcn_mfma_f32_16x16x32_bf16(afrag[ch], b, acc, 0, 0, 0);
        }
        float asv = asrc[ft * 16 + lo];
        float adv = adst[ft * 16 + lo];
#pragma unroll
        for (int r = 0; r < 4; ++r) {
            int m = m0 + quad * 4 + r;
            if (m < M) out[(size_t)m * HD + ft * 16 + lo] = f2bf(acc[r]);
            as_p[r] += acc[r] * asv;
            ad_p[r] += acc[r] * adv;
        }
    }
#pragma unroll
    for (int off = 1; off < 16; off <<= 1) {
#pragma unroll
        for (int r = 0; r < 4; ++r) {
            as_p[r] += __shfl_xor(as_p[r], off);
            ad_p[r] += __shfl_xor(ad_p[r], off);
        }
    }
    if (lo == 0) {
#pragma unroll
        for (int r = 0; r < 4; ++r) {
            int m = m0 + quad * 4 + r;
            if (m < M) { alpha_s[m] = as_p[r]; alpha_d[m] = ad_p[r]; }
        }
    }
}

// ================= fused edge-softmax + SpMM (wave per dst) | lstm nonlin tail ====

__global__ void gat_spmm(const unsigned short* __restrict__ h, const int* __restrict__ row_beg,
                         const int* __restrict__ row_end, const int* __restrict__ csr_src,
                         const float* __restrict__ alpha_s, const float* __restrict__ alpha_d,
                         const float* __restrict__ bias, unsigned short* __restrict__ outp,
                         const float* __restrict__ g_lstm,
                         const float* __restrict__ bihf, const float* __restrict__ bhhf,
                         const float* __restrict__ bihr, const float* __restrict__ bhhr,
                         float* __restrict__ z) {
    if (blockIdx.x >= AGG_GRID) {
        // lstm nonlinearity (only present in first spmm launch's grid)
        int idx = (blockIdx.x - AGG_GRID) * 256 + threadIdx.x;   // < 1024*128
        int bb = idx >> 7, jj = idx & 127;
        int dir = jj >> 6, j = jj & 63;
        const float* gb = g_lstm + (size_t)bb * LG + dir * 192;
        const float* bi = dir ? bihr : bihf;
        const float* bh = dir ? bhhr : bhhf;
        float gi = gb[j]        + bi[j]        + bh[j];
        float gg = gb[64 + j]   + bi[128 + j]  + bh[128 + j];
        float go = gb[128 + j]  + bi[192 + j]  + bh[192 + j];
        float c = sigmoidf_(gi) * tanhf(gg);
        z[(size_t)bb * 320 + 128 + jj] = sigmoidf_(go) * tanhf(c);
        return;
    }
    int w = (int)((blockIdx.x * (size_t)blockDim.x + threadIdx.x) >> 6);
    int lane = threadIdx.x & 63;
    if (w >= N_NODES) return;
    int grp = lane >> 4, l16 = lane & 15;
    int rs = row_beg[w], re = row_end[w];
    int deg = re - rs;
    float ad = alpha_d[w];
    float acc[8] = {0.f, 0.f, 0.f, 0.f, 0.f, 0.f, 0.f, 0.f};
    if (deg <= 64) {
        int s_reg = 0;
        float e = -1e30f;
        if (lane < deg) {
            s_reg = csr_src[rs + lane];
            float t0 = alpha_s[s_reg] + ad;
            e = (t0 > 0.f) ? t0 : 0.2f * t0;
        }
        float m = e;
#pragma unroll
        for (int off = 32; off; off >>= 1) m = fmaxf(m, __shfl_xor(m, off));
        float ex = (lane < deg) ? __expf(e - m) : 0.f;
        float den = ex;
#pragma unroll
        for (int off = 32; off; off >>= 1) den += __shfl_xor(den, off);
        float coef = ex / (den + 1e-16f);
        int i = rs + grp;
        // 4-deep batched gathers (ILP): same per-group sequential order as before
        for (; i + 12 < re; i += 16) {
            int idx = i - rs;
            float c0 = __shfl(coef, idx);       int s0 = __shfl(s_reg, idx);
            float c1 = __shfl(coef, idx + 4);   int s1 = __shfl(s_reg, idx + 4);
            float c2 = __shfl(coef, idx + 8);   int s2 = __shfl(s_reg, idx + 8);
            float c3 = __shfl(coef, idx + 12);  int s3 = __shfl(s_reg, idx + 12);
            ushort8 h0 = *(const ushort8*)&h[(size_t)s0 * HD + l16 * 8];
            ushort8 h1 = *(const ushort8*)&h[(size_t)s1 * HD + l16 * 8];
            ushort8 h2 = *(const ushort8*)&h[(size_t)s2 * HD + l16 * 8];
            ushort8 h3 = *(const ushort8*)&h[(size_t)s3 * HD + l16 * 8];
#pragma unroll
            for (int j = 0; j < 8; ++j) acc[j] += c0 * bf2f(h0[j]);
#pragma unroll
            for (int j = 0; j < 8; ++j) acc[j] += c1 * bf2f(h1[j]);
#pragma unroll
            for (int j = 0; j < 8; ++j) acc[j] += c2 * bf2f(h2[j]);
#pragma unroll
            for (int j = 0; j < 8; ++j) acc[j] += c3 * bf2f(h3[j]);
        }
        for (; i < re; i += 4) {
            int idx = i - rs;
            float c0 = __shfl(coef, idx);
            int   s0 = __shfl(s_reg, idx);
            ushort8 h0 = *(const ushort8*)&h[(size_t)s0 * HD + l16 * 8];
#pragma unroll
            for (int j = 0; j < 8; ++j) acc[j] += c0 * bf2f(h0[j]);
        }
    } else {
        float m = -1e30f;
        for (int i = rs + lane; i < re; i += 64) {
            int s = csr_src[i];
            float t0 = alpha_s[s] + ad;
            t0 = (t0 > 0.f) ? t0 : 0.2f * t0;
            m = fmaxf(m, t0);
        }
#pragma unroll
        for (int off = 32; off; off >>= 1) m = fmaxf(m, __shfl_xor(m, off));
        float den = 0.f;
        for (int i = rs + lane; i < re; i += 64) {
            int s = csr_src[i];
            float t0 = alpha_s[s] + ad;
            t0 = (t0 > 0.f) ? t0 : 0.2f * t0;
            den += __expf(t0 - m);
        }
#pragma unroll
        for (int off = 32; off; off >>= 1) den += __shfl_xor(den, off);
        float inv = 1.f / (den + 1e-16f);
        for (int i = rs + grp; i < re; i += 4) {
            int s = csr_src[i];
            float t0 = alpha_s[s] + ad;
            t0 = (t0 > 0.f) ? t0 : 0.2f * t0;
            float c = __expf(t0 - m) * inv;
            ushort8 hv = *(const ushort8*)&h[(size_t)s * HD + l16 * 8];
#pragma unroll
            for (int j = 0; j < 8; ++j) acc[j] += c * bf2f(hv[j]);
        }
    }
#pragma unroll
    for (int j = 0; j < 8; ++j) {
        acc[j] += __shfl_xor(acc[j], 16);
        acc[j] += __shfl_xor(acc[j], 32);
    }
    int f0 = l16 * 8 + grp * 2;
    float2 bv = *(const float2*)&bias[f0];
    float vx = fmaxf(acc[grp * 2]     + bv.x, 0.f);
    float vy = fmaxf(acc[grp * 2 + 1] + bv.y, 0.f);
    unsigned int pv = (unsigned int)f2bf(vx) | ((unsigned int)f2bf(vy) << 16);
    *(unsigned int*)&outp[(size_t)w * HD + f0] = pv;
}

// ================= mean pool per graph (bf16 in, 2x node ILP) =================

__global__ void pool_kernel(const unsigned short* __restrict__ h, const int* __restrict__ start,
                            float* __restrict__ z) {
    int w = (int)((blockIdx.x * (size_t)blockDim.x + threadIdx.x) >> 6);
    int lane = threadIdx.x & 63;
    if (w >= NB) return;
    int grp = lane >> 4, l16 = lane & 15;
    int s0 = start[w], s1 = start[w + 1];
    float acc[8] = {0.f, 0.f, 0.f, 0.f, 0.f, 0.f, 0.f, 0.f};
    int n = s0 + grp;
    for (; n + 4 < s1; n += 8) {
        ushort8 a = *(const ushort8*)&h[(size_t)n * HD + l16 * 8];
        ushort8 b = *(const ushort8*)&h[(size_t)(n + 4) * HD + l16 * 8];
#pragma unroll
        for (int j = 0; j < 8; ++j) acc[j] += bf2f(a[j]);
#pragma unroll
        for (int j = 0; j < 8; ++j) acc[j] += bf2f(b[j]);
    }
    if (n < s1) {
        ushort8 a = *(const ushort8*)&h[(size_t)n * HD + l16 * 8];
#pragma unroll
        for (int j = 0; j < 8; ++j) acc[j] += bf2f(a[j]);
    }
#pragma unroll
    for (int j = 0; j < 8; ++j) {
        acc[j] += __shfl_xor(acc[j], 16);
        acc[j] += __shfl_xor(acc[j], 32);
    }
    float inv = 1.f / fmaxf((float)(s1 - s0), 1.f);
    int f0 = l16 * 8 + grp * 2;
    *(float2*)&z[(size_t)w * 320 + f0] =
        make_float2(acc[grp * 2] * inv, acc[grp * 2 + 1] * inv);
}

// ================= fus1: z1pre = z @ fus1_W^T (no bias; cancels in BN) + column stats ====
// grid (64,4) x 256 thr: 16 rows x 64 cols, K=320 full

__global__ __launch_bounds__(256) void fus1_stats(const float* __restrict__ X,
                                                  const float* __restrict__ W1,
                                                  float* __restrict__ out,
                                                  float* __restrict__ colsum,
                                                  float* __restrict__ colsq) {
    __shared__ float Xs[16][33];
    __shared__ float Ws[64][33];
    __shared__ float cs[4][64];
    __shared__ float cq[4][64];
    int t = threadIdx.x;
    int r0 = blockIdx.x * 16;
    int fb = blockIdx.y * 64;
    const float* W = W1 + (size_t)fb * 320;
    int f = t & 63, rsub = t >> 6;
    float acc0 = 0.f, acc1 = 0.f, acc2 = 0.f, acc3 = 0.f;
    for (int kc = 0; kc < 320; kc += 32) {
        {
            int idx = t * 2, xr = idx >> 5, xk = idx & 31;
            const float2 v = *(const float2*)&X[(size_t)(r0 + xr) * 320 + kc + xk];
            Xs[xr][xk] = v.x; Xs[xr][xk + 1] = v.y;
        }
        {
            int wf = t >> 2, wk = (t & 3) * 8;
            const float4* p = (const float4*)&W[(size_t)wf * 320 + kc + wk];
            float4 a = p[0], b = p[1];
            Ws[wf][wk] = a.x; Ws[wf][wk + 1] = a.y; Ws[wf][wk + 2] = a.z; Ws[wf][wk + 3] = a.w;
            Ws[wf][wk + 4] = b.x; Ws[wf][wk + 5] = b.y; Ws[wf][wk + 6] = b.z; Ws[wf][wk + 7] = b.w;
        }
        __syncthreads();
#pragma unroll
        for (int k = 0; k < 32; ++k) {
            float w = Ws[f][k];
            acc0 += Xs[rsub][k] * w;
            acc1 += Xs[rsub + 4][k] * w;
            acc2 += Xs[rsub + 8][k] * w;
            acc3 += Xs[rsub + 12][k] * w;
        }
        __syncthreads();
    }
    out[(size_t)(r0 + rsub) * 256 + fb + f] = acc0;
    out[(size_t)(r0 + rsub + 4) * 256 + fb + f] = acc1;
    out[(size_t)(r0 + rsub + 8) * 256 + fb + f] = acc2;
    out[(size_t)(r0 + rsub + 12) * 256 + fb + f] = acc3;
    cs[rsub][f] = acc0 + acc1 + acc2 + acc3;
    cq[rsub][f] = acc0 * acc0 + acc1 * acc1 + acc2 * acc2 + acc3 * acc3;
    __syncthreads();
    if (rsub == 0) {
        atomicAdd(&colsum[fb + f], cs[0][f] + cs[1][f] + cs[2][f] + cs[3][f]);
        atomicAdd(&colsq[fb + f],  cq[0][f] + cq[1][f] + cq[2][f] + cq[3][f]);
    }
}

// ================= fus2+final with BN inline =================
// out = relu(bn(z1pre) ) @ ... : 64 blocks x 256 thr, 16 rows x 128 cols, K=256

__global__ __launch_bounds__(256) void fus2_final(const float* __restrict__ z1pre,
                                                  const float* __restrict__ colsum,
                                                  const float* __restrict__ colsq,
                                                  const float* __restrict__ fus_g,
                                                  const float* __restrict__ fus_bb,
                                                  const float* __restrict__ W2,
                                                  const float* __restrict__ b2,
                                                  const float* __restrict__ W3,
                                                  const float* __restrict__ b3,
                                                  float* __restrict__ out) {
    __shared__ float Xs[16][33];
    __shared__ float Ws[128][33];
    __shared__ float rowsum[16];
    __shared__ float sc_[256], sh_[256];
    int t = threadIdx.x;
    {
        float mu = colsum[t] * (1.f / 1024.f);
        float var = colsq[t] * (1.f / 1024.f) - mu * mu;
        float s = rsqrtf(var + 1e-5f) * fus_g[t];
        sc_[t] = s;
        sh_[t] = fus_bb[t] - mu * s;
    }
    __syncthreads();
    int r0 = blockIdx.x * 16;
    int f = t & 127, rh = t >> 7;
    float acc[8] = {0.f, 0.f, 0.f, 0.f, 0.f, 0.f, 0.f, 0.f};
    for (int kc = 0; kc < 256; kc += 32) {
        {
            int idx = t * 2, xr = idx >> 5, xk = idx & 31;
            float2 v = *(const float2*)&z1pre[(size_t)(r0 + xr) * 256 + kc + xk];
            Xs[xr][xk]     = fmaxf(v.x * sc_[kc + xk]     + sh_[kc + xk], 0.f);
            Xs[xr][xk + 1] = fmaxf(v.y * sc_[kc + xk + 1] + sh_[kc + xk + 1], 0.f);
        }
#pragma unroll
        for (int i = 0; i < 4; ++i) {
            int id2 = t + 256 * i;
            int wf = id2 >> 3, wk = (id2 & 7) * 4;
            *(float4*)&Ws[wf][wk] = *(const float4*)&W2[(size_t)wf * 256 + kc + wk];
        }
        __syncthreads();
#pragma unroll
        for (int k = 0; k < 32; ++k) {
            float w = Ws[f][k];
#pragma unroll
            for (int r = 0; r < 8; ++r) acc[r] += Xs[rh * 8 + r][k] * w;
        }
        __syncthreads();
    }
    float bv = b2[f], wv = W3[f];
    if (t < 16) rowsum[t] = 0.f;
    __syncthreads();
#pragma unroll
    for (int r = 0; r < 8; ++r) {
        float v = fmaxf(acc[r] + bv, 0.f) * wv;
#pragma unroll
        for (int off = 32; off; off >>= 1) v += __shfl_xor(v, off);
        if ((t & 63) == 0) atomicAdd(&rowsum[rh * 8 + r], v);
    }
    __syncthreads();
    if (t < 16) out[r0 + t] = rowsum[t] + b3[0];
}

// ================= launch =================

extern "C" void kernel_launch(void* const* d_in, const int* in_sizes, int n_in,
                              void* d_out, int out_size, void* d_ws, size_t ws_size,
                              hipStream_t stream) {
    const float* x        = (const float*)d_in[0];
    const int*   ei       = (const int*)d_in[1];
    const int*   batch    = (const int*)d_in[2];
    const float* esm      = (const float*)d_in[3];
    const float* tabf     = (const float*)d_in[4];
    const float* gat1_W   = (const float*)d_in[5];
    const float* gat1_as  = (const float*)d_in[6];
    const float* gat1_ad  = (const float*)d_in[7];
    const float* gat1_b   = (const float*)d_in[8];
    const float* gat2_W   = (const float*)d_in[9];
    const float* gat2_as  = (const float*)d_in[10];
    const float* gat2_ad  = (const float*)d_in[11];
    const float* gat2_b   = (const float*)d_in[12];
    const float* Wih_f    = (const float*)d_in[13];
    const float* bih_f    = (const float*)d_in[15];
    const float* bhh_f    = (const float*)d_in[16];
    const float* Wih_r    = (const float*)d_in[17];
    const float* bih_r    = (const float*)d_in[19];
    const float* bhh_r    = (const float*)d_in[20];
    const float* tab_W    = (const float*)d_in[21];
    const float* tab_b    = (const float*)d_in[22];
    const float* tab_g    = (const float*)d_in[23];
    const float* tab_bb   = (const float*)d_in[24];
    const float* fus1_W   = (const float*)d_in[25];
    const float* fus_g    = (const float*)d_in[27];
    const float* fus_bb   = (const float*)d_in[28];
    const float* fus2_W   = (const float*)d_in[29];
    const float* fus2_b   = (const float*)d_in[30];
    const float* fus3_W   = (const float*)d_in[31];
    const float* fus3_b   = (const float*)d_in[32];
    float* out = (float*)d_out;

    char* ws = (char*)d_ws;
    size_t off = 0;
    auto alloc = [&](size_t bytes) -> char* {
        char* p = ws + off;
        off += (bytes + 255) & ~(size_t)255;
        return p;
    };
    unsigned short* h0_bf = (unsigned short*)alloc((size_t)N_PAD * HD * 2);
    unsigned short* hA_bf = (unsigned short*)alloc((size_t)N_PAD * HD * 2);
    unsigned short* h2_bf = (unsigned short*)alloc((size_t)N_PAD * HD * 2);
    unsigned short* h_act = (unsigned short*)alloc((size_t)N_NODES * HD * 2);
    float* alpha_s = (float*)alloc((size_t)N_NODES * 4);
    float* alpha_d = (float*)alloc((size_t)N_NODES * 4);
    unsigned short* w2bf = (unsigned short*)alloc((size_t)HD * HD * 2);
    int*   row_beg = (int*)alloc((size_t)N_NODES * 4);
    int*   row_end = (int*)alloc((size_t)N_NODES * 4);
    int*   csr_src = (int*)alloc((size_t)NBUCK * CAP * 4);
    int*   pairs   = (int*)alloc((size_t)NBUCK * CAP * 4);
    int*   gstart  = (int*)alloc((size_t)(NB + 1) * 4);
    float* z1pre   = (float*)alloc((size_t)NB * 256 * 4);
    float* z       = (float*)alloc((size_t)NB * 320 * 4);     // fully written, no memset
    float* g_lstm  = (float*)alloc((size_t)NB * LG * 4);      // written by MFMA, no memset
    // zero-init group (contiguous, one memset): gcur, colsum, colsq
    int*   gcur    = (int*)alloc((size_t)NBUCK * 4);
    float* colsum  = (float*)alloc((size_t)256 * 4);
    float* colsq   = (float*)alloc((size_t)256 * 4);
    size_t zero_len = (size_t)((char*)colsq + 256 * 4 - (char*)gcur);
    hipMemsetAsync(gcur, 0, zero_len, stream);

    // 1) small-LDS front: scatter | gat1 MFMA (no LDS) | bounds | Wconv | tab
    megaA<<<SC_BLK + G1B + BND_BLK + WC_BLK + TAB_BLK, 256, 0, stream>>>(
        ei, gcur, pairs, x, gat1_W, gat1_as, gat1_ad, h0_bf, alpha_s, alpha_d,
        batch, gstart, gat2_W, w2bf,
        tabf, tab_W, tab_b, tab_g, tab_bb, z);

    // 2) CSR finalize | lstm MFMA (big LDS, few blocks)
    megaB<<<NBUCK + LSTM_B, 256, 0, stream>>>(gcur, pairs, row_beg, row_end, csr_src,
                                              esm, Wih_f, Wih_r, g_lstm);

    // 3) GAT layer 1 aggregation | lstm nonlinearity tail
    gat_spmm<<<AGG_GRID + NL_BLK, 256, 0, stream>>>(h0_bf, row_beg, row_end, csr_src,
                                                    alpha_s, alpha_d, gat1_b, hA_bf,
                                                    g_lstm, bih_f, bhh_f, bih_r, bhh_r, z);

    // 4) GAT2 linear (MFMA, alphas fused)
    gemm_mfma<<<N_PAD / 64, 256, 0, stream>>>(hA_bf, w2bf, gat2_as, gat2_ad,
                                              h2_bf, alpha_s, alpha_d, N_NODES);

    // 5) GAT layer 2 aggregation
    gat_spmm<<<AGG_GRID, 256, 0, stream>>>(h2_bf, row_beg, row_end, csr_src,
                                           alpha_s, alpha_d, gat2_b, h_act,
                                           g_lstm, bih_f, bhh_f, bih_r, bhh_r, z);

    // 6) mean pool -> z[:, 0:128)
    pool_kernel<<<(NB + 3) / 4, 256, 0, stream>>>(h_act, gstart, z);

    // 7) fus1 GEMM + BN column stats
    fus1_stats<<<dim3(64, 4), 256, 0, stream>>>(z, fus1_W, z1pre, colsum, colsq);

    // 8) BN+relu inline, fus2 GEMM, relu, final dot
    fus2_final<<<64, 256, 0, stream>>>(z1pre, colsum, colsq, fus_g, fus_bb,
                                       fus2_W, fus2_b, fus3_W, fus3_b, out);

    (void)in_sizes; (void)n_in; (void)out_size; (void)ws_size;
}

// Round 5
// 270.045 us; speedup vs baseline: 1.1549x; 1.1549x over previous
//
#include <hip/hip_runtime.h>
#include <hip/hip_bf16.h>

#define N_NODES 50000
#define N_PAD   50048
#define N_EDGES 800000
#define E_TOT   850000
#define NB      1024
#define ESM_DIM 480
#define HD      128
#define NBUCK   196          // buckets of 256 dst nodes
#define CAP     5120         // fixed bucket capacity (mean 4352 + 12 sigma)
#define EPB     3321         // edges per scatter block (256 blocks)
#define SC_BLK  256
#define CVT_BLK 256
#define BND_BLK 196
#define WC_BLK  16
#define TAB_BLK 4
#define G1B     782          // N_PAD / 64
#define LSTM_B  96           // 16 m-tiles x 6 n-tiles (64x64 out per block)
#define LG      384          // lstm gate cols kept (i,g,o per direction)
#define AGG_GRID 12500
#define NL_BLK  512

typedef short short8 __attribute__((ext_vector_type(8)));
typedef unsigned short ushort8 __attribute__((ext_vector_type(8)));
typedef float f32x4 __attribute__((ext_vector_type(4)));

__device__ __forceinline__ float bf2f(unsigned int u) {
    union { unsigned int i; float f; } c; c.i = u << 16; return c.f;
}
__device__ __forceinline__ unsigned short f2bf(float f) {
    union { float f; unsigned int i; } c; c.f = f;
    unsigned int i = c.i;
    return (unsigned short)((i + 0x7FFFu + ((i >> 16) & 1u)) >> 16);
}
__device__ __forceinline__ void split2(float v, unsigned short& h, unsigned short& l) {
    h = f2bf(v);
    l = f2bf(v - bf2f(h));
}

// ================= megaA parts =================

// scatter with per-block LDS count + global range reservation (no hist/scan stages)
__device__ void dev_scatter(const int* __restrict__ ei, int* __restrict__ gcur,
                            int* __restrict__ pairs, int blk) {
    __shared__ int hist[NBUCK];
    int t = threadIdx.x;
    for (int u = t; u < NBUCK; u += 256) hist[u] = 0;
    __syncthreads();
    int e0 = blk * EPB;
    int e1 = (e0 + EPB < E_TOT) ? e0 + EPB : E_TOT;
    for (int e = e0 + t; e < e1; e += 256) {
        int d = (e < N_EDGES) ? ei[N_EDGES + e] : (e - N_EDGES);
        atomicAdd(&hist[d >> 8], 1);
    }
    __syncthreads();
    for (int u = t; u < NBUCK; u += 256) {
        int c = hist[u];
        hist[u] = (c > 0) ? atomicAdd(&gcur[u], c) : 0;   // base within bucket
    }
    __syncthreads();
    for (int e = e0 + t; e < e1; e += 256) {
        int s, d;
        if (e < N_EDGES) { s = ei[e]; d = ei[N_EDGES + e]; }
        else             { s = d = e - N_EDGES; }
        int bu = d >> 8;
        int pos = atomicAdd(&hist[bu], 1);
        pairs[bu * CAP + pos] = s | ((d & 255) << 16);    // s < 65536
    }
}

// conversion role: esm -> bf16 hi/lo, gathered lstm W (i,g,o rows) -> bf16 hi/lo,
// gat1 W -> padded [128][32] bf16 hi/lo
__device__ void dev_cvt(const float* __restrict__ esm,
                        const float* __restrict__ Wf,
                        const float* __restrict__ Wr,
                        const float* __restrict__ W1,
                        unsigned short* __restrict__ esm_h, unsigned short* __restrict__ esm_l,
                        unsigned short* __restrict__ wg_h,  unsigned short* __restrict__ wg_l,
                        unsigned short* __restrict__ w1h,   unsigned short* __restrict__ w1l,
                        int blk) {
    int tid = blk * 256 + threadIdx.x;          // 0..65535
    // esm [1024][480] -> hi/lo, float4 units
    for (int u = tid; u < NB * 120; u += CVT_BLK * 256) {
        float4 v = ((const float4*)esm)[u];
        ushort4 h, l;
        split2(v.x, h.x, l.x); split2(v.y, h.y, l.y);
        split2(v.z, h.z, l.z); split2(v.w, h.w, l.w);
        ((ushort4*)esm_h)[u] = h; ((ushort4*)esm_l)[u] = l;
    }
    // gathered lstm weights: rows n in [0,384): dir = n>=192, rr = n%192
    // gate map rr: [0,64)=i, [64,128)=g, [128,192)=o  -> src row rr<64?rr:rr+64
    for (int u = tid; u < LG * 120; u += CVT_BLK * 256) {
        int n = u / 120, kk = u - n * 120;
        int rr = (n >= 192) ? n - 192 : n;
        const float* Ws = (n >= 192) ? Wr : Wf;
        int srow = (rr < 64) ? rr : rr + 64;
        float4 v = *(const float4*)&Ws[(size_t)srow * 480 + kk * 4];
        ushort4 h, l;
        split2(v.x, h.x, l.x); split2(v.y, h.y, l.y);
        split2(v.z, h.z, l.z); split2(v.w, h.w, l.w);
        ((ushort4*)wg_h)[u] = h; ((ushort4*)wg_l)[u] = l;
    }
    // gat1 W [128][21] -> [128][32] padded hi/lo
    for (int u = tid; u < 128 * 32; u += CVT_BLK * 256) {
        int f = u >> 5, k = u & 31;
        float v = (k < 21) ? W1[f * 21 + k] : 0.f;
        unsigned short h, l;
        split2(v, h, l);
        w1h[u] = h; w1l[u] = l;
    }
}

// tab branch: 4 blocks x 256 thr, block handles 16 cols; recompute (no big reg array)
__device__ void dev_tab4(const float* __restrict__ tf, const float* __restrict__ W,
                         const float* __restrict__ bias, const float* __restrict__ g,
                         const float* __restrict__ b, float* __restrict__ z, int blk) {
    __shared__ float ssum[16][16];
    __shared__ float ssq[16][16];
    int t = threadIdx.x;
    int rg = t >> 4, jl = t & 15;
    int j = blk * 16 + jl;
    float Wj[7];
#pragma unroll
    for (int k = 0; k < 7; ++k) Wj[k] = W[j * 7 + k];
    float bj = bias[j];
    float s = 0.f, q = 0.f;
    for (int rr = 0; rr < 64; ++rr) {
        int row = rg * 64 + rr;
        const float* xp = &tf[(size_t)row * 7];
        float a = bj;
#pragma unroll
        for (int k = 0; k < 7; ++k) a += xp[k] * Wj[k];
        s += a; q += a * a;
    }
    ssum[rg][jl] = s; ssq[rg][jl] = q;
    __syncthreads();
    for (int off = 8; off; off >>= 1) {
        if (rg < off) { ssum[rg][jl] += ssum[rg + off][jl]; ssq[rg][jl] += ssq[rg + off][jl]; }
        __syncthreads();
    }
    float mu = ssum[0][jl] * (1.f / 1024.f);
    float var = ssq[0][jl] * (1.f / 1024.f) - mu * mu;
    float sc = rsqrtf(var + 1e-5f) * g[j];
    float sh = b[j] - mu * sc;
    for (int rr = 0; rr < 64; ++rr) {
        int row = rg * 64 + rr;
        const float* xp = &tf[(size_t)row * 7];
        float a = bj;
#pragma unroll
        for (int k = 0; k < 7; ++k) a += xp[k] * Wj[k];
        z[(size_t)row * 320 + 256 + j] = fmaxf(a * sc + sh, 0.f);
    }
}

__global__ __launch_bounds__(256) void megaA(
        const int* __restrict__ ei, int* __restrict__ gcur, int* __restrict__ pairs,
        const float* __restrict__ esm, const float* __restrict__ Wih_f,
        const float* __restrict__ Wih_r, const float* __restrict__ gat1_W,
        unsigned short* __restrict__ esm_h, unsigned short* __restrict__ esm_l,
        unsigned short* __restrict__ wg_h,  unsigned short* __restrict__ wg_l,
        unsigned short* __restrict__ w1h,   unsigned short* __restrict__ w1l,
        const int* __restrict__ batch, int* __restrict__ gstart,
        const float* __restrict__ W2, unsigned short* __restrict__ Wb,
        const float* __restrict__ tf, const float* __restrict__ tab_W,
        const float* __restrict__ tab_b, const float* __restrict__ tab_g,
        const float* __restrict__ tab_bb, float* __restrict__ z) {
    int b = blockIdx.x, t = threadIdx.x;
    if (b < SC_BLK) {
        dev_scatter(ei, gcur, pairs, b);
    } else if (b < SC_BLK + CVT_BLK) {
        dev_cvt(esm, Wih_f, Wih_r, gat1_W, esm_h, esm_l, wg_h, wg_l, w1h, w1l, b - SC_BLK);
    } else if (b < SC_BLK + CVT_BLK + BND_BLK) {
        int i = (b - (SC_BLK + CVT_BLK)) * 256 + t;
        if (i >= N_NODES) return;
        int bb = batch[i];
        int bp = (i == 0) ? -1 : batch[i - 1];
        for (int g = bp + 1; g <= bb; ++g) gstart[g] = i;
        if (i == N_NODES - 1)
            for (int g = bb + 1; g <= NB; ++g) gstart[g] = N_NODES;
    } else if (b < SC_BLK + CVT_BLK + BND_BLK + WC_BLK) {
        int i = (b - (SC_BLK + CVT_BLK + BND_BLK)) * 256 + t;
        if (i >= 128 * 32) return;
        float4 v = ((const float4*)W2)[i];
        ((ushort4*)Wb)[i] = make_ushort4(f2bf(v.x), f2bf(v.y), f2bf(v.z), f2bf(v.w));
    } else {
        dev_tab4(tf, tab_W, tab_b, tab_g, tab_bb, z,
                 b - (SC_BLK + CVT_BLK + BND_BLK + WC_BLK));
    }
}

// ================= megaB: bucket CSR | lstm MFMA (LDS-staged) | gat1 MFMA =====

__device__ __forceinline__ float sigmoidf_(float x) { return 1.f / (1.f + __expf(-x)); }

// gat1 as split-bf16 MFMA (f32 accuracy): h = X @ W^T, fused alpha epilogue.
__device__ void dev_gat1_mfma(const float* __restrict__ X,
                              const unsigned short* __restrict__ w1h,
                              const unsigned short* __restrict__ w1l,
                              const float* __restrict__ asrc, const float* __restrict__ adst,
                              unsigned short* __restrict__ out,
                              float* __restrict__ alpha_s, float* __restrict__ alpha_d,
                              int blk) {
    int t = threadIdx.x;
    int wid = t >> 6, L = t & 63, quad = L >> 4, lo = L & 15;
    int m0 = blk * 64 + wid * 16;
    int row = m0 + lo;
    const float* xr = X + (size_t)row * 21;
    int kbase = quad * 8;
    bool valid = row < N_NODES;
    float xv[8];
#pragma unroll
    for (int j = 0; j < 8; ++j) {
        int k = kbase + j;
        xv[j] = (valid && k < 21) ? xr[k] : 0.f;
    }
    short8 ah, al;
#pragma unroll
    for (int j = 0; j < 8; ++j) {
        unsigned short h, l;
        split2(xv[j], h, l);
        ah[j] = (short)h; al[j] = (short)l;
    }
    float as_p[4] = {0.f, 0.f, 0.f, 0.f};
    float ad_p[4] = {0.f, 0.f, 0.f, 0.f};
#pragma unroll
    for (int ft = 0; ft < 8; ++ft) {
        short8 bh = *(const short8*)&w1h[(ft * 16 + lo) * 32 + kbase];
        short8 bl = *(const short8*)&w1l[(ft * 16 + lo) * 32 + kbase];
        f32x4 acc = {0.f, 0.f, 0.f, 0.f};
        acc = __builtin_amdgcn_mfma_f32_16x16x32_bf16(ah, bh, acc, 0, 0, 0);
        acc = __builtin_amdgcn_mfma_f32_16x16x32_bf16(al, bh, acc, 0, 0, 0);
        acc = __builtin_amdgcn_mfma_f32_16x16x32_bf16(ah, bl, acc, 0, 0, 0);
        float asv = asrc[ft * 16 + lo];
        float adv = adst[ft * 16 + lo];
#pragma unroll
        for (int r = 0; r < 4; ++r) {
            int m = m0 + quad * 4 + r;
            out[(size_t)m * HD + ft * 16 + lo] = f2bf(acc[r]);   // pad rows -> 0, always < N_PAD
            as_p[r] += acc[r] * asv;
            ad_p[r] += acc[r] * adv;
        }
    }
#pragma unroll
    for (int off = 1; off < 16; off <<= 1) {
#pragma unroll
        for (int r = 0; r < 4; ++r) {
            as_p[r] += __shfl_xor(as_p[r], off);
            ad_p[r] += __shfl_xor(ad_p[r], off);
        }
    }
    if (lo == 0) {
#pragma unroll
        for (int r = 0; r < 4; ++r) {
            int m = m0 + quad * 4 + r;
            if (m < N_NODES) { alpha_s[m] = as_p[r]; alpha_d[m] = ad_p[r]; }
        }
    }
}

// lstm gates: G[1024][384] = esm @ Wg^T (i,g,o), split-bf16 MFMA.
// 96 blocks: 16 m-tiles (64 rows) x 6 n-tiles (64 cols). B hi/lo staged in LDS
// per 96-wide K chunk, shared by all 4 waves (pad +8 ushorts -> ~2-way banks).
__device__ void dev_lstm_mfma(const unsigned short* __restrict__ Ah,
                              const unsigned short* __restrict__ Al,
                              const unsigned short* __restrict__ Bh,
                              const unsigned short* __restrict__ Bl,
                              float* __restrict__ G, int blk) {
    __shared__ unsigned short Bsh[64][104];
    __shared__ unsigned short Bsl[64][104];
    int t = threadIdx.x;
    int wid = t >> 6, L = t & 63, quad = L >> 4, lo = L & 15;
    int nt = blk % 6, mt = blk / 6;
    int m0 = mt * 64 + wid * 16;
    int n0 = nt * 64;
    f32x4 accs[4];
#pragma unroll
    for (int ft = 0; ft < 4; ++ft) accs[ft] = (f32x4){0.f, 0.f, 0.f, 0.f};
    const unsigned short* arh = Ah + (size_t)(m0 + lo) * ESM_DIM;
    const unsigned short* arl = Al + (size_t)(m0 + lo) * ESM_DIM;
    for (int c = 0; c < 5; ++c) {
        int k0c = c * 96;
        // per-wave A fragments for this chunk (issued before staging loads)
        short8 ah[3], al[3];
#pragma unroll
        for (int ks = 0; ks < 3; ++ks) {
            ah[ks] = *(const short8*)&arh[k0c + ks * 32 + quad * 8];
            al[ks] = *(const short8*)&arl[k0c + ks * 32 + quad * 8];
        }
        // cooperative stage of B tile: 64 rows x 96 cols, hi+lo
#pragma unroll
        for (int u = 0; u < 3; ++u) {
            int li = u * 2048 + t * 8;
            int row = li / 96, col = li % 96;
            *(ushort8*)&Bsh[row][col] =
                *(const ushort8*)&Bh[(size_t)(n0 + row) * ESM_DIM + k0c + col];
            *(ushort8*)&Bsl[row][col] =
                *(const ushort8*)&Bl[(size_t)(n0 + row) * ESM_DIM + k0c + col];
        }
        __syncthreads();
#pragma unroll
        for (int ks = 0; ks < 3; ++ks) {
#pragma unroll
            for (int ft = 0; ft < 4; ++ft) {
                short8 bh = *(const short8*)&Bsh[ft * 16 + lo][ks * 32 + quad * 8];
                short8 bl = *(const short8*)&Bsl[ft * 16 + lo][ks * 32 + quad * 8];
                accs[ft] = __builtin_amdgcn_mfma_f32_16x16x32_bf16(ah[ks], bh, accs[ft], 0, 0, 0);
                accs[ft] = __builtin_amdgcn_mfma_f32_16x16x32_bf16(al[ks], bh, accs[ft], 0, 0, 0);
                accs[ft] = __builtin_amdgcn_mfma_f32_16x16x32_bf16(ah[ks], bl, accs[ft], 0, 0, 0);
            }
        }
        __syncthreads();
    }
#pragma unroll
    for (int ft = 0; ft < 4; ++ft) {
#pragma unroll
        for (int r = 0; r < 4; ++r)
            G[(size_t)(m0 + quad * 4 + r) * LG + n0 + ft * 16 + lo] = accs[ft][r];
    }
}

__global__ __launch_bounds__(256) void megaB(
        const int* __restrict__ gcur, const int* __restrict__ pairs,
        int* __restrict__ row_beg, int* __restrict__ row_end, int* __restrict__ csr_src,
        const float* __restrict__ x,
        const unsigned short* __restrict__ w1h, const unsigned short* __restrict__ w1l,
        const float* __restrict__ gat1_as, const float* __restrict__ gat1_ad,
        unsigned short* __restrict__ h0, float* __restrict__ alpha_s, float* __restrict__ alpha_d,
        const unsigned short* __restrict__ esm_h, const unsigned short* __restrict__ esm_l,
        const unsigned short* __restrict__ wg_h,  const unsigned short* __restrict__ wg_l,
        float* __restrict__ g_lstm) {
    int b = blockIdx.x, t = threadIdx.x;
    if (b < NBUCK) {
        __shared__ int dc[256];
        __shared__ int wt[4];
        __shared__ int cur[256];
        int rs = b * CAP;
        int re = rs + gcur[b];
        dc[t] = 0;
        __syncthreads();
        // pass 1: per-dst histogram, 4-way unrolled loads (hide HBM/L2 latency)
        for (int i = rs + t; i < re; i += 1024) {
            int i1 = i + 256, i2 = i + 512, i3 = i + 768;
            int p0 = pairs[i];
            int p1 = (i1 < re) ? pairs[i1] : 0;
            int p2 = (i2 < re) ? pairs[i2] : 0;
            int p3 = (i3 < re) ? pairs[i3] : 0;
            atomicAdd(&dc[p0 >> 16], 1);
            if (i1 < re) atomicAdd(&dc[p1 >> 16], 1);
            if (i2 < re) atomicAdd(&dc[p2 >> 16], 1);
            if (i3 < re) atomicAdd(&dc[p3 >> 16], 1);
        }
        __syncthreads();
        int v = dc[t];
        int lane = t & 63, wid = t >> 6;
        int sc = v;
#pragma unroll
        for (int off = 1; off < 64; off <<= 1) {
            int n = __shfl_up(sc, off);
            if (lane >= off) sc += n;
        }
        if (lane == 63) wt[wid] = sc;
        __syncthreads();
        int pref = 0;
        for (int ww = 0; ww < wid; ++ww) pref += wt[ww];
        int beg = rs + pref + sc - v;
        int node = b * 256 + t;
        if (node < N_NODES) { row_beg[node] = beg; row_end[node] = beg + v; }
        cur[t] = beg;
        __syncthreads();
        // pass 2: positioning, 4-way unrolled loads
        for (int i = rs + t; i < re; i += 1024) {
            int i1 = i + 256, i2 = i + 512, i3 = i + 768;
            int p0 = pairs[i];
            int p1 = (i1 < re) ? pairs[i1] : 0;
            int p2 = (i2 < re) ? pairs[i2] : 0;
            int p3 = (i3 < re) ? pairs[i3] : 0;
            int pos0 = atomicAdd(&cur[p0 >> 16], 1);
            csr_src[pos0] = p0 & 0xFFFF;
            if (i1 < re) { int pos = atomicAdd(&cur[p1 >> 16], 1); csr_src[pos] = p1 & 0xFFFF; }
            if (i2 < re) { int pos = atomicAdd(&cur[p2 >> 16], 1); csr_src[pos] = p2 & 0xFFFF; }
            if (i3 < re) { int pos = atomicAdd(&cur[p3 >> 16], 1); csr_src[pos] = p3 & 0xFFFF; }
        }
    } else if (b < NBUCK + LSTM_B) {
        dev_lstm_mfma(esm_h, esm_l, wg_h, wg_l, g_lstm, b - NBUCK);
    } else {
        dev_gat1_mfma(x, w1h, w1l, gat1_as, gat1_ad, h0, alpha_s, alpha_d,
                      b - (NBUCK + LSTM_B));
    }
}

// ================= GAT2 linear: MFMA + fused alpha epilogue =================

__global__ __launch_bounds__(256) void gemm_mfma(const unsigned short* __restrict__ A,
                                                 const unsigned short* __restrict__ Wb,
                                                 const float* __restrict__ asrc,
                                                 const float* __restrict__ adst,
                                                 unsigned short* __restrict__ out,
                                                 float* __restrict__ alpha_s,
                                                 float* __restrict__ alpha_d, int M) {
    __shared__ unsigned short Wlds[128 * 136];
    int t = threadIdx.x;
    for (int u = t; u < 128 * 16; u += 256) {
        int row = u >> 4, seg = u & 15;
        *(ushort8*)&Wlds[row * 136 + seg * 8] = *(const ushort8*)&Wb[row * 128 + seg * 8];
    }
    __syncthreads();
    int wid = t >> 6, L = t & 63;
    int quad = L >> 4, lo = L & 15;
    int m0 = blockIdx.x * 64 + wid * 16;
    short8 afrag[4];
#pragma unroll
    for (int ch = 0; ch < 4; ++ch)
        afrag[ch] = *(const short8*)&A[(size_t)(m0 + lo) * HD + ch * 32 + quad * 8];
    float as_p[4] = {0.f, 0.f, 0.f, 0.f};
    float ad_p[4] = {0.f, 0.f, 0.f, 0.f};
#pragma unroll
    for (int ft = 0; ft < 8; ++ft) {
        f32x4 acc = {0.f, 0.f, 0.f, 0.f};
#pragma unroll
        for (int ch = 0; ch < 4; ++ch) {
            short8 b = *(const short8*)&Wlds[(ft * 16 + lo) * 136 + ch * 32 + quad * 8];
            acc = __builtin_amdgcn_mfma_f32_16x16x32_bf16(afrag[ch], b, acc, 0, 0, 0);
        }
        float asv = asrc[ft * 16 + lo];
        float adv = adst[ft * 16 + lo];
#pragma unroll
        for (int r = 0; r < 4; ++r) {
            int m = m0 + quad * 4 + r;
            if (m < M) out[(size_t)m * HD + ft * 16 + lo] = f2bf(acc[r]);
            as_p[r] += acc[r] * asv;
            ad_p[r] += acc[r] * adv;
        }
    }
#pragma unroll
    for (int off = 1; off < 16; off <<= 1) {
#pragma unroll
        for (int r = 0; r < 4; ++r) {
            as_p[r] += __shfl_xor(as_p[r], off);
            ad_p[r] += __shfl_xor(ad_p[r], off);
        }
    }
    if (lo == 0) {
#pragma unroll
        for (int r = 0; r < 4; ++r) {
            int m = m0 + quad * 4 + r;
            if (m < M) { alpha_s[m] = as_p[r]; alpha_d[m] = ad_p[r]; }
        }
    }
}

// ================= fused edge-softmax + SpMM (wave per dst) | lstm nonlin tail ====

__global__ void gat_spmm(const unsigned short* __restrict__ h, const int* __restrict__ row_beg,
                         const int* __restrict__ row_end, const int* __restrict__ csr_src,
                         const float* __restrict__ alpha_s, const float* __restrict__ alpha_d,
                         const float* __restrict__ bias, unsigned short* __restrict__ outp,
                         const float* __restrict__ g_lstm,
                         const float* __restrict__ bihf, const float* __restrict__ bhhf,
                         const float* __restrict__ bihr, const float* __restrict__ bhhr,
                         float* __restrict__ z) {
    if (blockIdx.x >= AGG_GRID) {
        // lstm nonlinearity (only present in first spmm launch's grid)
        int idx = (blockIdx.x - AGG_GRID) * 256 + threadIdx.x;   // < 1024*128
        int bb = idx >> 7, jj = idx & 127;
        int dir = jj >> 6, j = jj & 63;
        const float* gb = g_lstm + (size_t)bb * LG + dir * 192;
        const float* bi = dir ? bihr : bihf;
        const float* bh = dir ? bhhr : bhhf;
        float gi = gb[j]        + bi[j]        + bh[j];
        float gg = gb[64 + j]   + bi[128 + j]  + bh[128 + j];
        float go = gb[128 + j]  + bi[192 + j]  + bh[192 + j];
        float c = sigmoidf_(gi) * tanhf(gg);
        z[(size_t)bb * 320 + 128 + jj] = sigmoidf_(go) * tanhf(c);
        return;
    }
    int w = (int)((blockIdx.x * (size_t)blockDim.x + threadIdx.x) >> 6);
    int lane = threadIdx.x & 63;
    if (w >= N_NODES) return;
    int grp = lane >> 4, l16 = lane & 15;
    int rs = row_beg[w], re = row_end[w];
    int deg = re - rs;
    float ad = alpha_d[w];
    float acc[8] = {0.f, 0.f, 0.f, 0.f, 0.f, 0.f, 0.f, 0.f};
    if (deg <= 64) {
        int s_reg = 0;
        float e = -1e30f;
        if (lane < deg) {
            s_reg = csr_src[rs + lane];
            float t0 = alpha_s[s_reg] + ad;
            e = (t0 > 0.f) ? t0 : 0.2f * t0;
        }
        float m = e;
#pragma unroll
        for (int off = 32; off; off >>= 1) m = fmaxf(m, __shfl_xor(m, off));
        float ex = (lane < deg) ? __expf(e - m) : 0.f;
        float den = ex;
#pragma unroll
        for (int off = 32; off; off >>= 1) den += __shfl_xor(den, off);
        float coef = ex / (den + 1e-16f);
        int i = rs + grp;
        for (; i + 4 < re; i += 8) {
            int idx = i - rs;
            float c0 = __shfl(coef, idx);
            int   s0 = __shfl(s_reg, idx);
            float c1 = __shfl(coef, idx + 4);
            int   s1 = __shfl(s_reg, idx + 4);
            ushort8 h0 = *(const ushort8*)&h[(size_t)s0 * HD + l16 * 8];
            ushort8 h1 = *(const ushort8*)&h[(size_t)s1 * HD + l16 * 8];
#pragma unroll
            for (int j = 0; j < 8; ++j) acc[j] += c0 * bf2f(h0[j]);
#pragma unroll
            for (int j = 0; j < 8; ++j) acc[j] += c1 * bf2f(h1[j]);
        }
        if (i < re) {
            int idx = i - rs;
            float c0 = __shfl(coef, idx);
            int   s0 = __shfl(s_reg, idx);
            ushort8 h0 = *(const ushort8*)&h[(size_t)s0 * HD + l16 * 8];
#pragma unroll
            for (int j = 0; j < 8; ++j) acc[j] += c0 * bf2f(h0[j]);
        }
    } else {
        float m = -1e30f;
        for (int i = rs + lane; i < re; i += 64) {
            int s = csr_src[i];
            float t0 = alpha_s[s] + ad;
            t0 = (t0 > 0.f) ? t0 : 0.2f * t0;
            m = fmaxf(m, t0);
        }
#pragma unroll
        for (int off = 32; off; off >>= 1) m = fmaxf(m, __shfl_xor(m, off));
        float den = 0.f;
        for (int i = rs + lane; i < re; i += 64) {
            int s = csr_src[i];
            float t0 = alpha_s[s] + ad;
            t0 = (t0 > 0.f) ? t0 : 0.2f * t0;
            den += __expf(t0 - m);
        }
#pragma unroll
        for (int off = 32; off; off >>= 1) den += __shfl_xor(den, off);
        float inv = 1.f / (den + 1e-16f);
        for (int i = rs + grp; i < re; i += 4) {
            int s = csr_src[i];
            float t0 = alpha_s[s] + ad;
            t0 = (t0 > 0.f) ? t0 : 0.2f * t0;
            float c = __expf(t0 - m) * inv;
            ushort8 hv = *(const ushort8*)&h[(size_t)s * HD + l16 * 8];
#pragma unroll
            for (int j = 0; j < 8; ++j) acc[j] += c * bf2f(hv[j]);
        }
    }
#pragma unroll
    for (int j = 0; j < 8; ++j) {
        acc[j] += __shfl_xor(acc[j], 16);
        acc[j] += __shfl_xor(acc[j], 32);
    }
    int f0 = l16 * 8 + grp * 2;
    float2 bv = *(const float2*)&bias[f0];
    float vx = fmaxf(acc[grp * 2]     + bv.x, 0.f);
    float vy = fmaxf(acc[grp * 2 + 1] + bv.y, 0.f);
    unsigned int pv = (unsigned int)f2bf(vx) | ((unsigned int)f2bf(vy) << 16);
    *(unsigned int*)&outp[(size_t)w * HD + f0] = pv;
}

// ================= mean pool per graph (bf16 in, 2x node ILP) =================

__global__ void pool_kernel(const unsigned short* __restrict__ h, const int* __restrict__ start,
                            float* __restrict__ z) {
    int w = (int)((blockIdx.x * (size_t)blockDim.x + threadIdx.x) >> 6);
    int lane = threadIdx.x & 63;
    if (w >= NB) return;
    int grp = lane >> 4, l16 = lane & 15;
    int s0 = start[w], s1 = start[w + 1];
    float acc[8] = {0.f, 0.f, 0.f, 0.f, 0.f, 0.f, 0.f, 0.f};
    int n = s0 + grp;
    for (; n + 4 < s1; n += 8) {
        ushort8 a = *(const ushort8*)&h[(size_t)n * HD + l16 * 8];
        ushort8 b = *(const ushort8*)&h[(size_t)(n + 4) * HD + l16 * 8];
#pragma unroll
        for (int j = 0; j < 8; ++j) acc[j] += bf2f(a[j]);
#pragma unroll
        for (int j = 0; j < 8; ++j) acc[j] += bf2f(b[j]);
    }
    if (n < s1) {
        ushort8 a = *(const ushort8*)&h[(size_t)n * HD + l16 * 8];
#pragma unroll
        for (int j = 0; j < 8; ++j) acc[j] += bf2f(a[j]);
    }
#pragma unroll
    for (int j = 0; j < 8; ++j) {
        acc[j] += __shfl_xor(acc[j], 16);
        acc[j] += __shfl_xor(acc[j], 32);
    }
    float inv = 1.f / fmaxf((float)(s1 - s0), 1.f);
    int f0 = l16 * 8 + grp * 2;
    *(float2*)&z[(size_t)w * 320 + f0] =
        make_float2(acc[grp * 2] * inv, acc[grp * 2 + 1] * inv);
}

// ================= fus1 (MFMA): z1pre = z @ fus1_W^T + column stats ============
// grid (16,4): 64x64 out per block, K=320 in 5 chunks of 64; split-bf16 hi/lo.

__global__ __launch_bounds__(256) void fus1_mfma(const float* __restrict__ X,
                                                 const float* __restrict__ W1,
                                                 float* __restrict__ out,
                                                 float* __restrict__ colsum,
                                                 float* __restrict__ colsq) {
    __shared__ unsigned short Bsh[64][72];
    __shared__ unsigned short Bsl[64][72];
    __shared__ float cls[64], clq[64];
    int t = threadIdx.x;
    int wid = t >> 6, L = t & 63, quad = L >> 4, lo = L & 15;
    int m0 = blockIdx.x * 64 + wid * 16;
    int n0 = blockIdx.y * 64;
    if (t < 64) { cls[t] = 0.f; clq[t] = 0.f; }
    f32x4 accs[4];
#pragma unroll
    for (int ft = 0; ft < 4; ++ft) accs[ft] = (f32x4){0.f, 0.f, 0.f, 0.f};
    const float* ar = X + (size_t)(m0 + lo) * 320;
    for (int c = 0; c < 5; ++c) {
        int k0 = c * 64;
        // per-wave A fragments: f32 load + in-reg hi/lo split
        short8 ah[2], al[2];
#pragma unroll
        for (int ks = 0; ks < 2; ++ks) {
            const float* ap = &ar[k0 + ks * 32 + quad * 8];
            float4 v0 = *(const float4*)ap;
            float4 v1 = *(const float4*)(ap + 4);
            float av[8] = {v0.x, v0.y, v0.z, v0.w, v1.x, v1.y, v1.z, v1.w};
#pragma unroll
            for (int j = 0; j < 8; ++j) {
                unsigned short hh, ll;
                split2(av[j], hh, ll);
                ah[ks][j] = (short)hh; al[ks][j] = (short)ll;
            }
        }
        // cooperative stage of W1 tile: 64 rows x 64 cols f32 -> hi/lo
#pragma unroll
        for (int u = 0; u < 4; ++u) {
            int li = u * 256 + t;            // float4 units: 64*16 = 1024
            int row = li >> 4, col = (li & 15) * 4;
            float4 v = *(const float4*)&W1[(size_t)(n0 + row) * 320 + k0 + col];
            ushort4 hh, ll;
            split2(v.x, hh.x, ll.x); split2(v.y, hh.y, ll.y);
            split2(v.z, hh.z, ll.z); split2(v.w, hh.w, ll.w);
            *(ushort4*)&Bsh[row][col] = hh;
            *(ushort4*)&Bsl[row][col] = ll;
        }
        __syncthreads();
#pragma unroll
        for (int ks = 0; ks < 2; ++ks) {
#pragma unroll
            for (int ft = 0; ft < 4; ++ft) {
                short8 bh = *(const short8*)&Bsh[ft * 16 + lo][ks * 32 + quad * 8];
                short8 bl = *(const short8*)&Bsl[ft * 16 + lo][ks * 32 + quad * 8];
                accs[ft] = __builtin_amdgcn_mfma_f32_16x16x32_bf16(ah[ks], bh, accs[ft], 0, 0, 0);
                accs[ft] = __builtin_amdgcn_mfma_f32_16x16x32_bf16(al[ks], bh, accs[ft], 0, 0, 0);
                accs[ft] = __builtin_amdgcn_mfma_f32_16x16x32_bf16(ah[ks], bl, accs[ft], 0, 0, 0);
            }
        }
        __syncthreads();
    }
    // epilogue: store + per-column stats (sum over the wave's 16 rows, then block, then global)
#pragma unroll
    for (int ft = 0; ft < 4; ++ft) {
        float s = 0.f, q = 0.f;
#pragma unroll
        for (int r = 0; r < 4; ++r) {
            float v = accs[ft][r];
            out[(size_t)(m0 + quad * 4 + r) * 256 + n0 + ft * 16 + lo] = v;
            s += v; q += v * v;
        }
        s += __shfl_xor(s, 16); s += __shfl_xor(s, 32);
        q += __shfl_xor(q, 16); q += __shfl_xor(q, 32);
        if (quad == 0) {
            atomicAdd(&cls[ft * 16 + lo], s);
            atomicAdd(&clq[ft * 16 + lo], q);
        }
    }
    __syncthreads();
    if (t < 64) {
        atomicAdd(&colsum[n0 + t], cls[t]);
        atomicAdd(&colsq[n0 + t],  clq[t]);
    }
}

// ================= fus2+final (MFMA) with BN inline =========================
// 16 blocks: 64 rows x all 128 cols, K=256 in 4 chunks of 64; BN+relu in A-conv;
// epilogue: relu(+b2) * W3, in-register row reduce, direct store (no atomics).

__global__ __launch_bounds__(256) void fus2_mfma(const float* __restrict__ z1pre,
                                                 const float* __restrict__ colsum,
                                                 const float* __restrict__ colsq,
                                                 const float* __restrict__ fus_g,
                                                 const float* __restrict__ fus_bb,
                                                 const float* __restrict__ W2,
                                                 const float* __restrict__ b2,
                                                 const float* __restrict__ W3,
                                                 const float* __restrict__ b3,
                                                 float* __restrict__ out) {
    __shared__ unsigned short Bsh[128][72];
    __shared__ unsigned short Bsl[128][72];
    __shared__ float sc_[256], sh_[256];
    int t = threadIdx.x;
    {
        float mu = colsum[t] * (1.f / 1024.f);
        float var = colsq[t] * (1.f / 1024.f) - mu * mu;
        float s = rsqrtf(var + 1e-5f) * fus_g[t];
        sc_[t] = s;
        sh_[t] = fus_bb[t] - mu * s;
    }
    __syncthreads();
    int wid = t >> 6, L = t & 63, quad = L >> 4, lo = L & 15;
    int m0 = blockIdx.x * 64 + wid * 16;
    f32x4 accs[8];
#pragma unroll
    for (int ft = 0; ft < 8; ++ft) accs[ft] = (f32x4){0.f, 0.f, 0.f, 0.f};
    const float* ar = z1pre + (size_t)(m0 + lo) * 256;
    for (int c = 0; c < 4; ++c) {
        int k0 = c * 64;
        // per-wave A fragments: BN + relu + hi/lo split
        short8 ah[2], al[2];
#pragma unroll
        for (int ks = 0; ks < 2; ++ks) {
            int kb = k0 + ks * 32 + quad * 8;
            float4 v0 = *(const float4*)&ar[kb];
            float4 v1 = *(const float4*)&ar[kb + 4];
            float av[8] = {v0.x, v0.y, v0.z, v0.w, v1.x, v1.y, v1.z, v1.w};
#pragma unroll
            for (int j = 0; j < 8; ++j) {
                float xv = fmaxf(av[j] * sc_[kb + j] + sh_[kb + j], 0.f);
                unsigned short hh, ll;
                split2(xv, hh, ll);
                ah[ks][j] = (short)hh; al[ks][j] = (short)ll;
            }
        }
        // cooperative stage of W2 tile: 128 rows x 64 cols f32 -> hi/lo
#pragma unroll
        for (int u = 0; u < 8; ++u) {
            int li = u * 256 + t;            // float4 units: 128*16 = 2048
            int row = li >> 4, col = (li & 15) * 4;
            float4 v = *(const float4*)&W2[(size_t)row * 256 + k0 + col];
            ushort4 hh, ll;
            split2(v.x, hh.x, ll.x); split2(v.y, hh.y, ll.y);
            split2(v.z, hh.z, ll.z); split2(v.w, hh.w, ll.w);
            *(ushort4*)&Bsh[row][col] = hh;
            *(ushort4*)&Bsl[row][col] = ll;
        }
        __syncthreads();
#pragma unroll
        for (int ks = 0; ks < 2; ++ks) {
#pragma unroll
            for (int ft = 0; ft < 8; ++ft) {
                short8 bh = *(const short8*)&Bsh[ft * 16 + lo][ks * 32 + quad * 8];
                short8 bl = *(const short8*)&Bsl[ft * 16 + lo][ks * 32 + quad * 8];
                accs[ft] = __builtin_amdgcn_mfma_f32_16x16x32_bf16(ah[ks], bh, accs[ft], 0, 0, 0);
                accs[ft] = __builtin_amdgcn_mfma_f32_16x16x32_bf16(al[ks], bh, accs[ft], 0, 0, 0);
                accs[ft] = __builtin_amdgcn_mfma_f32_16x16x32_bf16(ah[ks], bl, accs[ft], 0, 0, 0);
            }
        }
        __syncthreads();
    }
    // epilogue: relu(+b2) * W3, row-reduce across 128 cols (ft in-reg, lo via shuffle)
    float b3v = b3[0];
    float b2v[8], w3v[8];
#pragma unroll
    for (int ft = 0; ft < 8; ++ft) {
        int col = ft * 16 + lo;
        b2v[ft] = b2[col];
        w3v[ft] = W3[col];
    }
#pragma unroll
    for (int r = 0; r < 4; ++r) {
        float rsum = 0.f;
#pragma unroll
        for (int ft = 0; ft < 8; ++ft)
            rsum += fmaxf(accs[ft][r] + b2v[ft], 0.f) * w3v[ft];
        rsum += __shfl_xor(rsum, 1);
        rsum += __shfl_xor(rsum, 2);
        rsum += __shfl_xor(rsum, 4);
        rsum += __shfl_xor(rsum, 8);
        if (lo == 0) out[m0 + quad * 4 + r] = rsum + b3v;
    }
}

// ================= launch =================

extern "C" void kernel_launch(void* const* d_in, const int* in_sizes, int n_in,
                              void* d_out, int out_size, void* d_ws, size_t ws_size,
                              hipStream_t stream) {
    const float* x        = (const float*)d_in[0];
    const int*   ei       = (const int*)d_in[1];
    const int*   batch    = (const int*)d_in[2];
    const float* esm      = (const float*)d_in[3];
    const float* tabf     = (const float*)d_in[4];
    const float* gat1_W   = (const float*)d_in[5];
    const float* gat1_as  = (const float*)d_in[6];
    const float* gat1_ad  = (const float*)d_in[7];
    const float* gat1_b   = (const float*)d_in[8];
    const float* gat2_W   = (const float*)d_in[9];
    const float* gat2_as  = (const float*)d_in[10];
    const float* gat2_ad  = (const float*)d_in[11];
    const float* gat2_b   = (const float*)d_in[12];
    const float* Wih_f    = (const float*)d_in[13];
    const float* bih_f    = (const float*)d_in[15];
    const float* bhh_f    = (const float*)d_in[16];
    const float* Wih_r    = (const float*)d_in[17];
    const float* bih_r    = (const float*)d_in[19];
    const float* bhh_r    = (const float*)d_in[20];
    const float* tab_W    = (const float*)d_in[21];
    const float* tab_b    = (const float*)d_in[22];
    const float* tab_g    = (const float*)d_in[23];
    const float* tab_bb   = (const float*)d_in[24];
    const float* fus1_W   = (const float*)d_in[25];
    const float* fus_g    = (const float*)d_in[27];
    const float* fus_bb   = (const float*)d_in[28];
    const float* fus2_W   = (const float*)d_in[29];
    const float* fus2_b   = (const float*)d_in[30];
    const float* fus3_W   = (const float*)d_in[31];
    const float* fus3_b   = (const float*)d_in[32];
    float* out = (float*)d_out;

    char* ws = (char*)d_ws;
    size_t off = 0;
    auto alloc = [&](size_t bytes) -> char* {
        char* p = ws + off;
        off += (bytes + 255) & ~(size_t)255;
        return p;
    };
    unsigned short* h0_bf = (unsigned short*)alloc((size_t)N_PAD * HD * 2);
    unsigned short* hA_bf = (unsigned short*)alloc((size_t)N_PAD * HD * 2);
    unsigned short* h2_bf = (unsigned short*)alloc((size_t)N_PAD * HD * 2);
    unsigned short* h_act = (unsigned short*)alloc((size_t)N_NODES * HD * 2);
    float* alpha_s = (float*)alloc((size_t)N_NODES * 4);
    float* alpha_d = (float*)alloc((size_t)N_NODES * 4);
    unsigned short* w2bf = (unsigned short*)alloc((size_t)HD * HD * 2);
    int*   row_beg = (int*)alloc((size_t)N_NODES * 4);
    int*   row_end = (int*)alloc((size_t)N_NODES * 4);
    int*   csr_src = (int*)alloc((size_t)NBUCK * CAP * 4);
    int*   pairs   = (int*)alloc((size_t)NBUCK * CAP * 4);
    int*   gstart  = (int*)alloc((size_t)(NB + 1) * 4);
    float* z1pre   = (float*)alloc((size_t)NB * 256 * 4);
    float* z       = (float*)alloc((size_t)NB * 320 * 4);     // fully written, no memset
    float* g_lstm  = (float*)alloc((size_t)NB * LG * 4);      // written by MFMA, no memset
    unsigned short* esm_h = (unsigned short*)alloc((size_t)NB * ESM_DIM * 2);
    unsigned short* esm_l = (unsigned short*)alloc((size_t)NB * ESM_DIM * 2);
    unsigned short* wg_h  = (unsigned short*)alloc((size_t)LG * ESM_DIM * 2);
    unsigned short* wg_l  = (unsigned short*)alloc((size_t)LG * ESM_DIM * 2);
    unsigned short* w1h   = (unsigned short*)alloc((size_t)128 * 32 * 2);
    unsigned short* w1l   = (unsigned short*)alloc((size_t)128 * 32 * 2);
    // zero-init group (contiguous, one memset): gcur, colsum, colsq
    int*   gcur    = (int*)alloc((size_t)NBUCK * 4);
    float* colsum  = (float*)alloc((size_t)256 * 4);
    float* colsq   = (float*)alloc((size_t)256 * 4);
    size_t zero_len = (size_t)((char*)colsq + 256 * 4 - (char*)gcur);
    hipMemsetAsync(gcur, 0, zero_len, stream);

    // 1) independent front: edge scatter+reserve | bf16 conversions | bounds | Wconv | tab
    megaA<<<SC_BLK + CVT_BLK + BND_BLK + WC_BLK + TAB_BLK, 256, 0, stream>>>(
        ei, gcur, pairs, esm, Wih_f, Wih_r, gat1_W,
        esm_h, esm_l, wg_h, wg_l, w1h, w1l,
        batch, gstart, gat2_W, w2bf,
        tabf, tab_W, tab_b, tab_g, tab_bb, z);

    // 2) CSR finalize | lstm gates MFMA (LDS-staged) | gat1 MFMA (+alphas)
    megaB<<<NBUCK + LSTM_B + G1B, 256, 0, stream>>>(
        gcur, pairs, row_beg, row_end, csr_src,
        x, w1h, w1l, gat1_as, gat1_ad, h0_bf, alpha_s, alpha_d,
        esm_h, esm_l, wg_h, wg_l, g_lstm);

    // 3) GAT layer 1 aggregation | lstm nonlinearity tail
    gat_spmm<<<AGG_GRID + NL_BLK, 256, 0, stream>>>(h0_bf, row_beg, row_end, csr_src,
                                                    alpha_s, alpha_d, gat1_b, hA_bf,
                                                    g_lstm, bih_f, bhh_f, bih_r, bhh_r, z);

    // 4) GAT2 linear (MFMA, alphas fused)
    gemm_mfma<<<N_PAD / 64, 256, 0, stream>>>(hA_bf, w2bf, gat2_as, gat2_ad,
                                              h2_bf, alpha_s, alpha_d, N_NODES);

    // 5) GAT layer 2 aggregation
    gat_spmm<<<AGG_GRID, 256, 0, stream>>>(h2_bf, row_beg, row_end, csr_src,
                                           alpha_s, alpha_d, gat2_b, h_act,
                                           g_lstm, bih_f, bhh_f, bih_r, bhh_r, z);

    // 6) mean pool -> z[:, 0:128)
    pool_kernel<<<(NB + 3) / 4, 256, 0, stream>>>(h_act, gstart, z);

    // 7) fus1 MFMA GEMM + BN column stats
    fus1_mfma<<<dim3(16, 4), 256, 0, stream>>>(z, fus1_W, z1pre, colsum, colsq);

    // 8) fus2 MFMA (BN+relu inline) + final dot
    fus2_mfma<<<16, 256, 0, stream>>>(z1pre, colsum, colsq, fus_g, fus_bb,
                                      fus2_W, fus2_b, fus3_W, fus3_b, out);

    (void)in_sizes; (void)n_in; (void)out_size; (void)ws_size;
}